// Round 5
// baseline (908.197 us; speedup 1.0000x reference)
//
#include <hip/hip_runtime.h>
#include <math.h>

#define N_NODES 10000
#define N_EDGES 160000
#define NEL 10
#define C 64
#define NB 8
#define SHD 9
#define MLPH 16
#define CSH 576
#define R_MAX 5.0f
#define INV_AVG 0.03125f
#define SCAN_CH 40    // 256*40 = 10240 >= N_NODES
#define GRID_MSG 1024 // 4 blocks/CU (LDS-limited), %8==0 for XCD chunking

__device__ __forceinline__ float silu_f(float v) {
    return v / (1.0f + __expf(-v));
}

// ---------------------------------------------------------------------------
// K1: per-edge geometry + radial MLP, compact active edges, degree histogram
// ---------------------------------------------------------------------------
__global__ __launch_bounds__(256) void k_edge(
    const float* __restrict__ pos, const float* __restrict__ shifts,
    const int* __restrict__ ei, const float* __restrict__ Wr1,
    int* __restrict__ cnt, int* __restrict__ deg,
    int* __restrict__ act_snd, int* __restrict__ act_rcv,
    float* __restrict__ act_sh, float* __restrict__ act_h0, float* __restrict__ act_h1)
{
    int e = blockIdx.x * 256 + threadIdx.x;
    int snd = ei[e];
    int rcv = ei[N_EDGES + e];
    float vx = pos[rcv * 3 + 0] - pos[snd * 3 + 0] + shifts[e * 3 + 0];
    float vy = pos[rcv * 3 + 1] - pos[snd * 3 + 1] + shifts[e * 3 + 1];
    float vz = pos[rcv * 3 + 2] - pos[snd * 3 + 2] + shifts[e * 3 + 2];
    float r = sqrtf(vx * vx + vy * vy + vz * vz) + 1e-9f;
    float x = r / R_MAX;
    bool active = x < 1.0f;

    unsigned long long m = __ballot(active);
    int lane = threadIdx.x & 63;
    int base = 0;
    if (m) {
        int leader = __ffsll((unsigned long long)m) - 1;
        if (lane == leader) base = atomicAdd(cnt, __popcll(m));
        base = __shfl(base, leader);
    }
    if (!active) return;

    int p = base + __popcll(m & ((1ull << lane) - 1ull));
    act_snd[p] = snd;
    act_rcv[p] = rcv;
    atomicAdd(&deg[rcv], 1);

    // spherical harmonics (l<=2)
    float inv_r = 1.0f / r;
    float ux = vx * inv_r, uy = vy * inv_r, uz = vz * inv_r;
    const float s3 = 1.7320508075688772f;
    const float s5 = 2.23606797749979f;
    const float s15 = 3.872983346207417f;
    act_sh[p * 9 + 0] = 1.0f;
    act_sh[p * 9 + 1] = s3 * ux;
    act_sh[p * 9 + 2] = s3 * uy;
    act_sh[p * 9 + 3] = s3 * uz;
    act_sh[p * 9 + 4] = s15 * ux * uy;
    act_sh[p * 9 + 5] = s15 * uy * uz;
    act_sh[p * 9 + 6] = 0.5f * s5 * (3.0f * uz * uz - 1.0f);
    act_sh[p * 9 + 7] = s15 * ux * uz;
    act_sh[p * 9 + 8] = 0.5f * s15 * (ux * ux - uy * uy);

    // radial: bessel * polynomial cutoff (p=6)
    float x6 = x * x * x; x6 = x6 * x6;
    float x7 = x6 * x;
    float x8 = x7 * x;
    float fc = 1.0f - 28.0f * x6 + 48.0f * x7 - 21.0f * x8;
    float theta = 3.14159265358979323846f * r / R_MAX;
    float s1 = sinf(theta), c1 = cosf(theta);
    float ef[NB];
    float sn = s1, cn = c1;
    float scale = 0.6324555320336759f * inv_r * fc;   // sqrt(2/R_MAX)/r*fc
    ef[0] = scale * sn;
    #pragma unroll
    for (int n = 1; n < NB; n++) {
        float sn1 = sn * c1 + cn * s1;
        float cn1 = cn * c1 - sn * s1;
        sn = sn1; cn = cn1;
        ef[n] = scale * sn;
    }

    #pragma unroll
    for (int t = 0; t < 2; t++) {
        float* dst = (t == 0) ? act_h0 : act_h1;
        const float* W = Wr1 + t * NB * MLPH;
        #pragma unroll
        for (int mm = 0; mm < MLPH; mm++) {
            float acc = 0.0f;
            #pragma unroll
            for (int b = 0; b < NB; b++) acc += ef[b] * W[b * MLPH + mm];
            dst[p * MLPH + mm] = silu_f(acc);
        }
    }
}

// ---------------------------------------------------------------------------
// K1b: exclusive scan of deg -> cursor  (single block)
// ---------------------------------------------------------------------------
__global__ __launch_bounds__(256) void k_scan(
    const int* __restrict__ deg, int* __restrict__ cursor)
{
    __shared__ int part[256];
    int tid = threadIdx.x;
    int base = tid * SCAN_CH;
    int s = 0;
    for (int i = 0; i < SCAN_CH; i++) {
        int idx = base + i;
        if (idx < N_NODES) s += deg[idx];
    }
    part[tid] = s;
    __syncthreads();
    for (int off = 1; off < 256; off <<= 1) {
        int v = (tid >= off) ? part[tid - off] : 0;
        __syncthreads();
        part[tid] += v;
        __syncthreads();
    }
    int run = part[tid] - s;
    for (int i = 0; i < SCAN_CH; i++) {
        int idx = base + i;
        if (idx < N_NODES) {
            cursor[idx] = run;
            run += deg[idx];
        }
    }
}

// ---------------------------------------------------------------------------
// K1c: scatter-permute active-edge payloads into CSR (receiver-sorted) order
// ---------------------------------------------------------------------------
__global__ __launch_bounds__(256) void k_scatter(
    const int* __restrict__ cnt, const int* __restrict__ act_snd,
    const int* __restrict__ act_rcv, const float* __restrict__ act_sh,
    const float* __restrict__ act_h0, const float* __restrict__ act_h1,
    int* __restrict__ cursor,
    int* __restrict__ csnd, int* __restrict__ crcv, float* __restrict__ csh,
    float* __restrict__ chid0, float* __restrict__ chid1)
{
    int i = blockIdx.x * 256 + threadIdx.x;
    if (i >= *cnt) return;
    int rcv = act_rcv[i];
    int pos = atomicAdd(&cursor[rcv], 1);
    csnd[pos] = act_snd[i];
    crcv[pos] = rcv;
    #pragma unroll
    for (int s = 0; s < SHD; s++) csh[pos * SHD + s] = act_sh[i * SHD + s];
    #pragma unroll
    for (int m = 0; m < MLPH; m++) chid0[pos * MLPH + m] = act_h0[i * MLPH + m];
    #pragma unroll
    for (int m = 0; m < MLPH; m++) chid1[pos * MLPH + m] = act_h1[i * MLPH + m];
}

// ---------------------------------------------------------------------------
// K2: node embedding h = node_attrs @ W_embed ; out[0..N) = node_attrs @ ae
// ---------------------------------------------------------------------------
__global__ __launch_bounds__(256) void k_embed(
    const float* __restrict__ na, const float* __restrict__ We,
    const float* __restrict__ ae, float* __restrict__ h, float* __restrict__ out)
{
    int i = blockIdx.x * 256 + threadIdx.x;
    int n = i >> 6, c = i & 63;
    float acc = 0.0f, e0 = 0.0f;
    #pragma unroll
    for (int k = 0; k < NEL; k++) {
        float a = na[n * NEL + k];
        acc += a * We[k * C + c];
        e0 += a * ae[k];
    }
    h[i] = acc;
    if (c == 0) out[n] = e0;
}

// ---------------------------------------------------------------------------
// K3: h_up = h @ W_up[t]  +  grid-stride zeroing of agg (fused memset)
// ---------------------------------------------------------------------------
__global__ __launch_bounds__(256) void k_up(
    const float* __restrict__ h, const float* __restrict__ Wup,
    float* __restrict__ hup, float* __restrict__ agg_zero)
{
    int tid = blockIdx.x * 256 + threadIdx.x;
    float4 z = make_float4(0.f, 0.f, 0.f, 0.f);
    for (int i = tid; i < N_NODES * CSH / 4; i += (N_NODES / 4) * 256)
        ((float4*)agg_zero)[i] = z;

    __shared__ float Wl[C * C];
    for (int i = threadIdx.x; i < C * C; i += 256) Wl[i] = Wup[i];
    __syncthreads();
    int o = threadIdx.x & 63, g = threadIdx.x >> 6;
    int n = blockIdx.x * 4 + g;
    const float* hr = h + n * C;
    float acc = 0.0f;
    #pragma unroll 8
    for (int c = 0; c < C; c++) acc += hr[c] * Wl[c * C + o];
    hup[n * C + o] = acc;
}

// ---------------------------------------------------------------------------
// K4 (hot): edge-parallel persistent blocks over CSR-sorted edges.
// XCD-chunked work assignment; register pre-reduction across same-receiver
// edges; per-edge gathers hoisted above the 16-iter MLP loop.
// ---------------------------------------------------------------------------
__global__ __launch_bounds__(256, 4) void k_msg2(
    const int* __restrict__ cnt, const int* __restrict__ csnd,
    const int* __restrict__ crcv, const float* __restrict__ csh,
    const float* __restrict__ chid, const float* __restrict__ Wr2,
    const float* __restrict__ hup, float* __restrict__ agg)
{
    __shared__ float Wl[MLPH * CSH];   // 36 KB
    for (int i = threadIdx.x; i < MLPH * CSH; i += 256) Wl[i] = Wr2[i];
    __syncthreads();

    int lane = threadIdx.x & 63;
    int w = threadIdx.x >> 6;
    int nAct = *cnt;
    int G = (nAct + 3) >> 2;

    int xcd = blockIdx.x & 7;
    int sub = blockIdx.x >> 3;         // 0..127
    int Gx = (G + 7) >> 3;
    int gbeg = xcd * Gx;
    int gend = gbeg + Gx; if (gend > G) gend = G;

    int c9[9], s9[9];
    {
        int c = lane / 9, s = lane - c * 9;
        #pragma unroll
        for (int jj = 0; jj < 9; jj++) {
            c9[jj] = c; s9[jj] = s;
            c += 7; s += 1;
            if (s >= 9) { s -= 9; c += 1; }
        }
    }

    for (int g = gbeg + sub * 4 + w; g < gend; g += 512) {
        int e0 = g << 2;
        int nv = nAct - e0; if (nv > 4) nv = 4;

        int rcvq[4];
        float hupq[4], shq[4];
        #pragma unroll
        for (int q = 0; q < 4; q++) {
            int kq = e0 + (q < nv ? q : nv - 1);
            rcvq[q] = crcv[kq];
            int snd = csnd[kq];
            hupq[q] = hup[snd * C + lane];
            shq[q] = (lane < SHD) ? csh[kq * SHD + lane] : 0.0f;
        }
        int e = lane >> 4;
        float hidS = chid[(e0 + (e < nv ? e : nv - 1)) * MLPH + (lane & 15)];

        float tw0[9], tw1[9], tw2[9], tw3[9];
        #pragma unroll
        for (int jj = 0; jj < 9; jj++) { tw0[jj] = 0.f; tw1[jj] = 0.f; tw2[jj] = 0.f; tw3[jj] = 0.f; }

        #pragma unroll
        for (int m = 0; m < MLPH; m++) {
            float hm0 = __shfl(hidS, m);
            float hm1 = __shfl(hidS, 16 + m);
            float hm2 = __shfl(hidS, 32 + m);
            float hm3 = __shfl(hidS, 48 + m);
            #pragma unroll
            for (int jj = 0; jj < 9; jj++) {
                float wv = Wl[m * CSH + lane + (jj << 6)];
                tw0[jj] += hm0 * wv;
                tw1[jj] += hm1 * wv;
                tw2[jj] += hm2 * wv;
                tw3[jj] += hm3 * wv;
            }
        }

        float acc[9];
        int curRcv = rcvq[0];
        #pragma unroll
        for (int jj = 0; jj < 9; jj++) {
            float mult = __shfl(hupq[0], c9[jj]) * __shfl(shq[0], s9[jj]);
            acc[jj] = tw0[jj] * mult;
        }
        #pragma unroll
        for (int q = 1; q < 4; q++) {
            if (q < nv) {
                const float* tw = (q == 1) ? tw1 : (q == 2) ? tw2 : tw3;
                if (rcvq[q] != curRcv) {
                    float* ag = agg + (size_t)curRcv * CSH + lane;
                    #pragma unroll
                    for (int jj = 0; jj < 9; jj++) atomicAdd(ag + (jj << 6), acc[jj]);
                    curRcv = rcvq[q];
                    #pragma unroll
                    for (int jj = 0; jj < 9; jj++) {
                        float mult = __shfl(hupq[q], c9[jj]) * __shfl(shq[q], s9[jj]);
                        acc[jj] = tw[jj] * mult;
                    }
                } else {
                    #pragma unroll
                    for (int jj = 0; jj < 9; jj++) {
                        float mult = __shfl(hupq[q], c9[jj]) * __shfl(shq[q], s9[jj]);
                        acc[jj] += tw[jj] * mult;
                    }
                }
            }
        }
        float* ag = agg + (size_t)curRcv * CSH + lane;
        #pragma unroll
        for (int jj = 0; jj < 9; jj++) atomicAdd(ag + (jj << 6), acc[jj]);
    }
}

// ---------------------------------------------------------------------------
// K5: h_new = (agg/32) @ W_mix[t] + h @ W_self[t], fused readout.
// ---------------------------------------------------------------------------
template <int RMODE>
__global__ __launch_bounds__(256) void k_mix(
    const float* __restrict__ agg, const float* __restrict__ h,
    const float* __restrict__ Wmix, const float* __restrict__ Wself,
    float* __restrict__ hnew,
    const float* __restrict__ wread, const float* __restrict__ Wm1,
    const float* __restrict__ wm2, float* __restrict__ rep)
{
    __shared__ float Al[16 * CSH];   // 36 KB
    __shared__ float Hl[16 * C];     // 4 KB
    int nb = blockIdx.x * 16;
    for (int i = threadIdx.x; i < 16 * CSH; i += 256) Al[i] = agg[nb * CSH + i] * INV_AVG;
    for (int i = threadIdx.x; i < 16 * C; i += 256) Hl[i] = h[nb * C + i];
    __syncthreads();

    int o = threadIdx.x & 63, g = threadIdx.x >> 6;
    float acc[4] = {0.0f, 0.0f, 0.0f, 0.0f};
    for (int cs = 0; cs < CSH; cs++) {
        float w = Wmix[cs * C + o];
        #pragma unroll
        for (int q = 0; q < 4; q++) acc[q] += Al[(g + 4 * q) * CSH + cs] * w;
    }
    for (int c = 0; c < C; c++) {
        float w = Wself[c * C + o];
        #pragma unroll
        for (int q = 0; q < 4; q++) acc[q] += Hl[(g + 4 * q) * C + c] * w;
    }
    #pragma unroll
    for (int q = 0; q < 4; q++) hnew[(nb + g + 4 * q) * C + o] = acc[q];

    if (RMODE == 0) {
        float wr = wread[o];
        #pragma unroll
        for (int q = 0; q < 4; q++) {
            float v = acc[q] * wr;
            #pragma unroll
            for (int off = 32; off; off >>= 1) v += __shfl_xor(v, off);
            if (o == 0) rep[nb + g + 4 * q] = v;
        }
    } else {
        __syncthreads();
        float* Hn = Al;   // reuse as [16][64]
        #pragma unroll
        for (int q = 0; q < 4; q++) Hn[(g + 4 * q) * C + o] = acc[q];
        __syncthreads();
        int nl = threadIdx.x >> 4;
        int m = threadIdx.x & 15;
        float a2 = 0.0f;
        #pragma unroll 16
        for (int c = 0; c < C; c++) a2 += Hn[nl * C + c] * Wm1[c * MLPH + m];
        float rv = silu_f(a2) * wm2[m];
        #pragma unroll
        for (int off = 8; off; off >>= 1) rv += __shfl_xor(rv, off);
        if (m == 0) rep[nb + nl] = rv;
    }
}

// ---------------------------------------------------------------------------
extern "C" void kernel_launch(void* const* d_in, const int* in_sizes, int n_in,
                              void* d_out, int out_size, void* d_ws, size_t ws_size,
                              hipStream_t stream) {
    const float* pos    = (const float*)d_in[0];
    const float* na     = (const float*)d_in[1];
    const float* shifts = (const float*)d_in[2];
    const int*   ei     = (const int*)d_in[3];
    const float* ae     = (const float*)d_in[4];
    const float* We     = (const float*)d_in[5];
    const float* Wup    = (const float*)d_in[6];
    const float* Wr1    = (const float*)d_in[7];
    const float* Wr2    = (const float*)d_in[8];
    const float* Wmix   = (const float*)d_in[9];
    const float* Wself  = (const float*)d_in[10];
    const float* wread  = (const float*)d_in[11];
    const float* Wm1    = (const float*)d_in[12];
    const float* wm2    = (const float*)d_in[13];
    float* out = (float*)d_out;

    char* ws = (char*)d_ws;
    size_t off = 0;
    auto alloc = [&](size_t bytes) {
        off = (off + 255) & ~(size_t)255;
        void* p = ws + off;
        off += bytes;
        return p;
    };
    int*   cnt     = (int*)alloc(4);
    int*   deg     = (int*)alloc((size_t)N_NODES * 4);
    int*   cursor  = (int*)alloc((size_t)N_NODES * 4);
    int*   act_snd = (int*)alloc((size_t)N_EDGES * 4);
    int*   act_rcv = (int*)alloc((size_t)N_EDGES * 4);
    float* act_sh  = (float*)alloc((size_t)N_EDGES * 9 * 4);
    float* act_h0  = (float*)alloc((size_t)N_EDGES * 16 * 4);
    float* act_h1  = (float*)alloc((size_t)N_EDGES * 16 * 4);
    int*   csnd    = (int*)alloc((size_t)N_EDGES * 4);
    int*   crcv    = (int*)alloc((size_t)N_EDGES * 4);
    float* csh     = (float*)alloc((size_t)N_EDGES * 9 * 4);
    float* chid0   = (float*)alloc((size_t)N_EDGES * 16 * 4);
    float* chid1   = (float*)alloc((size_t)N_EDGES * 16 * 4);
    float* hA      = (float*)alloc((size_t)N_NODES * C * 4);
    float* hB      = (float*)alloc((size_t)N_NODES * C * 4);
    float* hup     = (float*)alloc((size_t)N_NODES * C * 4);
    float* agg     = (float*)alloc((size_t)N_NODES * CSH * 4);

    hipMemsetAsync(cnt, 0, 4, stream);
    hipMemsetAsync(deg, 0, (size_t)N_NODES * 4, stream);

    k_edge<<<N_EDGES / 256, 256, 0, stream>>>(pos, shifts, ei, Wr1, cnt, deg,
                                              act_snd, act_rcv, act_sh, act_h0, act_h1);
    k_scan<<<1, 256, 0, stream>>>(deg, cursor);
    k_scatter<<<N_EDGES / 256, 256, 0, stream>>>(cnt, act_snd, act_rcv, act_sh,
                                                 act_h0, act_h1, cursor,
                                                 csnd, crcv, csh, chid0, chid1);
    k_embed<<<(N_NODES * C) / 256, 256, 0, stream>>>(na, We, ae, hA, out);

    // ---- layer t = 0 ----
    k_up<<<N_NODES / 4, 256, 0, stream>>>(hA, Wup, hup, agg);
    k_msg2<<<GRID_MSG, 256, 0, stream>>>(cnt, csnd, crcv, csh, chid0, Wr2, hup, agg);
    k_mix<0><<<N_NODES / 16, 256, 0, stream>>>(agg, hA, Wmix, Wself, hB,
                                               wread, Wm1, wm2, out + N_NODES);

    // ---- layer t = 1 ----
    k_up<<<N_NODES / 4, 256, 0, stream>>>(hB, Wup + C * C, hup, agg);
    k_msg2<<<GRID_MSG, 256, 0, stream>>>(cnt, csnd, crcv, csh, chid1,
                                         Wr2 + MLPH * CSH, hup, agg);
    k_mix<1><<<N_NODES / 16, 256, 0, stream>>>(agg, hB, Wmix + C * SHD * C,
                                               Wself + C * C, hA,
                                               wread, Wm1, wm2, out + 2 * N_NODES);
}

// Round 6
// 305.510 us; speedup vs baseline: 2.9727x; 2.9727x over previous
//
#include <hip/hip_runtime.h>
#include <math.h>

#define N_NODES 10000
#define N_EDGES 160000
#define NEL 10
#define C 64
#define NB 8
#define SHD 9
#define MLPH 16
#define CSH 576
#define R_MAX 5.0f
#define INV_AVG 0.03125f
#define SCAN_CH 40    // 256*40 = 10240 >= N_NODES
#define GRID_MSG 1024 // %8==0 for XCD chunking

__device__ __forceinline__ float silu_f(float v) {
    return v / (1.0f + __expf(-v));
}

// ---------------------------------------------------------------------------
// K1: per-edge geometry + radial MLP, compact active edges, degree histogram
// ---------------------------------------------------------------------------
__global__ __launch_bounds__(256) void k_edge(
    const float* __restrict__ pos, const float* __restrict__ shifts,
    const int* __restrict__ ei, const float* __restrict__ Wr1,
    int* __restrict__ cnt, int* __restrict__ deg,
    int* __restrict__ act_snd, int* __restrict__ act_rcv,
    float* __restrict__ act_sh, float* __restrict__ act_h0, float* __restrict__ act_h1)
{
    int e = blockIdx.x * 256 + threadIdx.x;
    int snd = ei[e];
    int rcv = ei[N_EDGES + e];
    float vx = pos[rcv * 3 + 0] - pos[snd * 3 + 0] + shifts[e * 3 + 0];
    float vy = pos[rcv * 3 + 1] - pos[snd * 3 + 1] + shifts[e * 3 + 1];
    float vz = pos[rcv * 3 + 2] - pos[snd * 3 + 2] + shifts[e * 3 + 2];
    float r = sqrtf(vx * vx + vy * vy + vz * vz) + 1e-9f;
    float x = r / R_MAX;
    bool active = x < 1.0f;

    unsigned long long m = __ballot(active);
    int lane = threadIdx.x & 63;
    int base = 0;
    if (m) {
        int leader = __ffsll((unsigned long long)m) - 1;
        if (lane == leader) base = atomicAdd(cnt, __popcll(m));
        base = __shfl(base, leader);
    }
    if (!active) return;

    int p = base + __popcll(m & ((1ull << lane) - 1ull));
    act_snd[p] = snd;
    act_rcv[p] = rcv;
    atomicAdd(&deg[rcv], 1);

    // spherical harmonics (l<=2)
    float inv_r = 1.0f / r;
    float ux = vx * inv_r, uy = vy * inv_r, uz = vz * inv_r;
    const float s3 = 1.7320508075688772f;
    const float s5 = 2.23606797749979f;
    const float s15 = 3.872983346207417f;
    act_sh[p * 9 + 0] = 1.0f;
    act_sh[p * 9 + 1] = s3 * ux;
    act_sh[p * 9 + 2] = s3 * uy;
    act_sh[p * 9 + 3] = s3 * uz;
    act_sh[p * 9 + 4] = s15 * ux * uy;
    act_sh[p * 9 + 5] = s15 * uy * uz;
    act_sh[p * 9 + 6] = 0.5f * s5 * (3.0f * uz * uz - 1.0f);
    act_sh[p * 9 + 7] = s15 * ux * uz;
    act_sh[p * 9 + 8] = 0.5f * s15 * (ux * ux - uy * uy);

    // radial: bessel * polynomial cutoff (p=6)
    float x6 = x * x * x; x6 = x6 * x6;
    float x7 = x6 * x;
    float x8 = x7 * x;
    float fc = 1.0f - 28.0f * x6 + 48.0f * x7 - 21.0f * x8;
    float theta = 3.14159265358979323846f * r / R_MAX;
    float s1 = sinf(theta), c1 = cosf(theta);
    float ef[NB];
    float sn = s1, cn = c1;
    float scale = 0.6324555320336759f * inv_r * fc;   // sqrt(2/R_MAX)/r*fc
    ef[0] = scale * sn;
    #pragma unroll
    for (int n = 1; n < NB; n++) {
        float sn1 = sn * c1 + cn * s1;
        float cn1 = cn * c1 - sn * s1;
        sn = sn1; cn = cn1;
        ef[n] = scale * sn;
    }

    #pragma unroll
    for (int t = 0; t < 2; t++) {
        float* dst = (t == 0) ? act_h0 : act_h1;
        const float* W = Wr1 + t * NB * MLPH;
        #pragma unroll
        for (int mm = 0; mm < MLPH; mm++) {
            float acc = 0.0f;
            #pragma unroll
            for (int b = 0; b < NB; b++) acc += ef[b] * W[b * MLPH + mm];
            dst[p * MLPH + mm] = silu_f(acc);
        }
    }
}

// ---------------------------------------------------------------------------
// K1b: exclusive scan of deg -> cursor  (single block)
// ---------------------------------------------------------------------------
__global__ __launch_bounds__(256) void k_scan(
    const int* __restrict__ deg, int* __restrict__ cursor)
{
    __shared__ int part[256];
    int tid = threadIdx.x;
    int base = tid * SCAN_CH;
    int s = 0;
    for (int i = 0; i < SCAN_CH; i++) {
        int idx = base + i;
        if (idx < N_NODES) s += deg[idx];
    }
    part[tid] = s;
    __syncthreads();
    for (int off = 1; off < 256; off <<= 1) {
        int v = (tid >= off) ? part[tid - off] : 0;
        __syncthreads();
        part[tid] += v;
        __syncthreads();
    }
    int run = part[tid] - s;
    for (int i = 0; i < SCAN_CH; i++) {
        int idx = base + i;
        if (idx < N_NODES) {
            cursor[idx] = run;
            run += deg[idx];
        }
    }
}

// ---------------------------------------------------------------------------
// K1c: scatter-permute active-edge payloads into CSR (receiver-sorted) order
// ---------------------------------------------------------------------------
__global__ __launch_bounds__(256) void k_scatter(
    const int* __restrict__ cnt, const int* __restrict__ act_snd,
    const int* __restrict__ act_rcv, const float* __restrict__ act_sh,
    const float* __restrict__ act_h0, const float* __restrict__ act_h1,
    int* __restrict__ cursor,
    int* __restrict__ csnd, int* __restrict__ crcv, float* __restrict__ csh,
    float* __restrict__ chid0, float* __restrict__ chid1)
{
    int i = blockIdx.x * 256 + threadIdx.x;
    if (i >= *cnt) return;
    int rcv = act_rcv[i];
    int pos = atomicAdd(&cursor[rcv], 1);
    csnd[pos] = act_snd[i];
    crcv[pos] = rcv;
    #pragma unroll
    for (int s = 0; s < SHD; s++) csh[pos * SHD + s] = act_sh[i * SHD + s];
    #pragma unroll
    for (int m = 0; m < MLPH; m++) chid0[pos * MLPH + m] = act_h0[i * MLPH + m];
    #pragma unroll
    for (int m = 0; m < MLPH; m++) chid1[pos * MLPH + m] = act_h1[i * MLPH + m];
}

// ---------------------------------------------------------------------------
// K2: node embedding h = node_attrs @ W_embed ; out[0..N) = node_attrs @ ae
// ---------------------------------------------------------------------------
__global__ __launch_bounds__(256) void k_embed(
    const float* __restrict__ na, const float* __restrict__ We,
    const float* __restrict__ ae, float* __restrict__ h, float* __restrict__ out)
{
    int i = blockIdx.x * 256 + threadIdx.x;
    int n = i >> 6, c = i & 63;
    float acc = 0.0f, e0 = 0.0f;
    #pragma unroll
    for (int k = 0; k < NEL; k++) {
        float a = na[n * NEL + k];
        acc += a * We[k * C + c];
        e0 += a * ae[k];
    }
    h[i] = acc;
    if (c == 0) out[n] = e0;
}

// ---------------------------------------------------------------------------
// K3: h_up = h @ W_up[t]  +  grid-stride zeroing of agg (fused memset)
// ---------------------------------------------------------------------------
__global__ __launch_bounds__(256) void k_up(
    const float* __restrict__ h, const float* __restrict__ Wup,
    float* __restrict__ hup, float* __restrict__ agg_zero)
{
    int tid = blockIdx.x * 256 + threadIdx.x;
    float4 z = make_float4(0.f, 0.f, 0.f, 0.f);
    for (int i = tid; i < N_NODES * CSH / 4; i += (N_NODES / 4) * 256)
        ((float4*)agg_zero)[i] = z;

    __shared__ float Wl[C * C];
    for (int i = threadIdx.x; i < C * C; i += 256) Wl[i] = Wup[i];
    __syncthreads();
    int o = threadIdx.x & 63, g = threadIdx.x >> 6;
    int n = blockIdx.x * 4 + g;
    const float* hr = h + n * C;
    float acc = 0.0f;
    #pragma unroll 8
    for (int c = 0; c < C; c++) acc += hr[c] * Wl[c * C + o];
    hup[n * C + o] = acc;
}

// ---------------------------------------------------------------------------
// K4 (hot): edge-parallel over CSR-sorted edges; XCD-chunked ranges;
// register pre-reduction across same-receiver edges. NO min-wave clause
// (R4's (256,4) capped VGPR at 64 -> scratch spill -> 778MB HBM fetch).
// Per-edge hup/sh loads kept inside the flush loop to bound live state.
// ---------------------------------------------------------------------------
__global__ __launch_bounds__(256) void k_msg2(
    const int* __restrict__ cnt, const int* __restrict__ csnd,
    const int* __restrict__ crcv, const float* __restrict__ csh,
    const float* __restrict__ chid, const float* __restrict__ Wr2,
    const float* __restrict__ hup, float* __restrict__ agg)
{
    __shared__ float Wl[MLPH * CSH];   // 36 KB
    for (int i = threadIdx.x; i < MLPH * CSH; i += 256) Wl[i] = Wr2[i];
    __syncthreads();

    int lane = threadIdx.x & 63;
    int w = threadIdx.x >> 6;
    int nAct = *cnt;
    int G = (nAct + 3) >> 2;

    int xcd = blockIdx.x & 7;
    int sub = blockIdx.x >> 3;         // 0..127
    int Gx = (G + 7) >> 3;
    int gbeg = xcd * Gx;
    int gend = gbeg + Gx; if (gend > G) gend = G;

    int c9[9], s9[9];
    {
        int c = lane / 9, s = lane - c * 9;
        #pragma unroll
        for (int jj = 0; jj < 9; jj++) {
            c9[jj] = c; s9[jj] = s;
            c += 7; s += 1;
            if (s >= 9) { s -= 9; c += 1; }
        }
    }

    for (int g = gbeg + sub * 4 + w; g < gend; g += 512) {
        int e0 = g << 2;
        int nv = nAct - e0; if (nv > 4) nv = 4;

        // packed hidden load: 4 edges x 16 hidden units across the wave
        int e = lane >> 4;
        float hidS = chid[(e0 + (e < nv ? e : nv - 1)) * MLPH + (lane & 15)];

        float tw0[9], tw1[9], tw2[9], tw3[9];
        #pragma unroll
        for (int jj = 0; jj < 9; jj++) { tw0[jj] = 0.f; tw1[jj] = 0.f; tw2[jj] = 0.f; tw3[jj] = 0.f; }

        #pragma unroll
        for (int m = 0; m < MLPH; m++) {
            float hm0 = __shfl(hidS, m);
            float hm1 = __shfl(hidS, 16 + m);
            float hm2 = __shfl(hidS, 32 + m);
            float hm3 = __shfl(hidS, 48 + m);
            #pragma unroll
            for (int jj = 0; jj < 9; jj++) {
                float wv = Wl[m * CSH + lane + (jj << 6)];
                tw0[jj] += hm0 * wv;
                tw1[jj] += hm1 * wv;
                tw2[jj] += hm2 * wv;
                tw3[jj] += hm3 * wv;
            }
        }

        // register pre-reduction; flush on receiver change (wave-uniform)
        float acc[9];
        int curRcv = -1;
        #pragma unroll
        for (int q = 0; q < 4; q++) {
            if (q < nv) {                      // wave-uniform guard
                int kq = e0 + q;
                int rcv = crcv[kq];
                int snd = csnd[kq];
                float hupS = hup[snd * C + lane];
                float shS = (lane < SHD) ? csh[kq * SHD + lane] : 0.0f;
                const float* tw = (q == 0) ? tw0 : (q == 1) ? tw1 : (q == 2) ? tw2 : tw3;
                if (rcv != curRcv) {
                    if (curRcv >= 0) {
                        float* ag = agg + (size_t)curRcv * CSH + lane;
                        #pragma unroll
                        for (int jj = 0; jj < 9; jj++) atomicAdd(ag + (jj << 6), acc[jj]);
                    }
                    curRcv = rcv;
                    #pragma unroll
                    for (int jj = 0; jj < 9; jj++) {
                        float mult = __shfl(hupS, c9[jj]) * __shfl(shS, s9[jj]);
                        acc[jj] = tw[jj] * mult;
                    }
                } else {
                    #pragma unroll
                    for (int jj = 0; jj < 9; jj++) {
                        float mult = __shfl(hupS, c9[jj]) * __shfl(shS, s9[jj]);
                        acc[jj] += tw[jj] * mult;
                    }
                }
            }
        }
        float* ag = agg + (size_t)curRcv * CSH + lane;
        #pragma unroll
        for (int jj = 0; jj < 9; jj++) atomicAdd(ag + (jj << 6), acc[jj]);
    }
}

// ---------------------------------------------------------------------------
// K5: h_new = (agg/32) @ W_mix[t] + h @ W_self[t], fused readout.
// ---------------------------------------------------------------------------
template <int RMODE>
__global__ __launch_bounds__(256) void k_mix(
    const float* __restrict__ agg, const float* __restrict__ h,
    const float* __restrict__ Wmix, const float* __restrict__ Wself,
    float* __restrict__ hnew,
    const float* __restrict__ wread, const float* __restrict__ Wm1,
    const float* __restrict__ wm2, float* __restrict__ rep)
{
    __shared__ float Al[16 * CSH];   // 36 KB
    __shared__ float Hl[16 * C];     // 4 KB
    int nb = blockIdx.x * 16;
    for (int i = threadIdx.x; i < 16 * CSH; i += 256) Al[i] = agg[nb * CSH + i] * INV_AVG;
    for (int i = threadIdx.x; i < 16 * C; i += 256) Hl[i] = h[nb * C + i];
    __syncthreads();

    int o = threadIdx.x & 63, g = threadIdx.x >> 6;
    float acc[4] = {0.0f, 0.0f, 0.0f, 0.0f};
    for (int cs = 0; cs < CSH; cs++) {
        float w = Wmix[cs * C + o];
        #pragma unroll
        for (int q = 0; q < 4; q++) acc[q] += Al[(g + 4 * q) * CSH + cs] * w;
    }
    for (int c = 0; c < C; c++) {
        float w = Wself[c * C + o];
        #pragma unroll
        for (int q = 0; q < 4; q++) acc[q] += Hl[(g + 4 * q) * C + c] * w;
    }
    #pragma unroll
    for (int q = 0; q < 4; q++) hnew[(nb + g + 4 * q) * C + o] = acc[q];

    if (RMODE == 0) {
        float wr = wread[o];
        #pragma unroll
        for (int q = 0; q < 4; q++) {
            float v = acc[q] * wr;
            #pragma unroll
            for (int off = 32; off; off >>= 1) v += __shfl_xor(v, off);
            if (o == 0) rep[nb + g + 4 * q] = v;
        }
    } else {
        __syncthreads();
        float* Hn = Al;   // reuse as [16][64]
        #pragma unroll
        for (int q = 0; q < 4; q++) Hn[(g + 4 * q) * C + o] = acc[q];
        __syncthreads();
        int nl = threadIdx.x >> 4;
        int m = threadIdx.x & 15;
        float a2 = 0.0f;
        #pragma unroll 16
        for (int c = 0; c < C; c++) a2 += Hn[nl * C + c] * Wm1[c * MLPH + m];
        float rv = silu_f(a2) * wm2[m];
        #pragma unroll
        for (int off = 8; off; off >>= 1) rv += __shfl_xor(rv, off);
        if (m == 0) rep[nb + nl] = rv;
    }
}

// ---------------------------------------------------------------------------
extern "C" void kernel_launch(void* const* d_in, const int* in_sizes, int n_in,
                              void* d_out, int out_size, void* d_ws, size_t ws_size,
                              hipStream_t stream) {
    const float* pos    = (const float*)d_in[0];
    const float* na     = (const float*)d_in[1];
    const float* shifts = (const float*)d_in[2];
    const int*   ei     = (const int*)d_in[3];
    const float* ae     = (const float*)d_in[4];
    const float* We     = (const float*)d_in[5];
    const float* Wup    = (const float*)d_in[6];
    const float* Wr1    = (const float*)d_in[7];
    const float* Wr2    = (const float*)d_in[8];
    const float* Wmix   = (const float*)d_in[9];
    const float* Wself  = (const float*)d_in[10];
    const float* wread  = (const float*)d_in[11];
    const float* Wm1    = (const float*)d_in[12];
    const float* wm2    = (const float*)d_in[13];
    float* out = (float*)d_out;

    char* ws = (char*)d_ws;
    size_t off = 0;
    auto alloc = [&](size_t bytes) {
        off = (off + 255) & ~(size_t)255;
        void* p = ws + off;
        off += bytes;
        return p;
    };
    int*   cnt     = (int*)alloc(4);
    int*   deg     = (int*)alloc((size_t)N_NODES * 4);
    int*   cursor  = (int*)alloc((size_t)N_NODES * 4);
    int*   act_snd = (int*)alloc((size_t)N_EDGES * 4);
    int*   act_rcv = (int*)alloc((size_t)N_EDGES * 4);
    float* act_sh  = (float*)alloc((size_t)N_EDGES * 9 * 4);
    float* act_h0  = (float*)alloc((size_t)N_EDGES * 16 * 4);
    float* act_h1  = (float*)alloc((size_t)N_EDGES * 16 * 4);
    int*   csnd    = (int*)alloc((size_t)N_EDGES * 4);
    int*   crcv    = (int*)alloc((size_t)N_EDGES * 4);
    float* csh     = (float*)alloc((size_t)N_EDGES * 9 * 4);
    float* chid0   = (float*)alloc((size_t)N_EDGES * 16 * 4);
    float* chid1   = (float*)alloc((size_t)N_EDGES * 16 * 4);
    float* hA      = (float*)alloc((size_t)N_NODES * C * 4);
    float* hB      = (float*)alloc((size_t)N_NODES * C * 4);
    float* hup     = (float*)alloc((size_t)N_NODES * C * 4);
    float* agg     = (float*)alloc((size_t)N_NODES * CSH * 4);

    hipMemsetAsync(cnt, 0, 4, stream);
    hipMemsetAsync(deg, 0, (size_t)N_NODES * 4, stream);

    k_edge<<<N_EDGES / 256, 256, 0, stream>>>(pos, shifts, ei, Wr1, cnt, deg,
                                              act_snd, act_rcv, act_sh, act_h0, act_h1);
    k_scan<<<1, 256, 0, stream>>>(deg, cursor);
    k_scatter<<<N_EDGES / 256, 256, 0, stream>>>(cnt, act_snd, act_rcv, act_sh,
                                                 act_h0, act_h1, cursor,
                                                 csnd, crcv, csh, chid0, chid1);
    k_embed<<<(N_NODES * C) / 256, 256, 0, stream>>>(na, We, ae, hA, out);

    // ---- layer t = 0 ----
    k_up<<<N_NODES / 4, 256, 0, stream>>>(hA, Wup, hup, agg);
    k_msg2<<<GRID_MSG, 256, 0, stream>>>(cnt, csnd, crcv, csh, chid0, Wr2, hup, agg);
    k_mix<0><<<N_NODES / 16, 256, 0, stream>>>(agg, hA, Wmix, Wself, hB,
                                               wread, Wm1, wm2, out + N_NODES);

    // ---- layer t = 1 ----
    k_up<<<N_NODES / 4, 256, 0, stream>>>(hB, Wup + C * C, hup, agg);
    k_msg2<<<GRID_MSG, 256, 0, stream>>>(cnt, csnd, crcv, csh, chid1,
                                         Wr2 + MLPH * CSH, hup, agg);
    k_mix<1><<<N_NODES / 16, 256, 0, stream>>>(agg, hB, Wmix + C * SHD * C,
                                               Wself + C * C, hA,
                                               wread, Wm1, wm2, out + 2 * N_NODES);
}